// Round 9
// baseline (153.055 us; speedup 1.0000x reference)
//
#include <hip/hip_runtime.h>
#include <hip/hip_bf16.h>

// Two pairwise MLPs (ChG, DG) over 1024x1024 pairs, then A_chg @ A_gd, sigmoid.
// Outputs concat: [0:1M) sigmoid(A_chd), [1M:2M) A_chg, [2M:3M) A_gd (fp32).
//
// R22: branch serves W1 A-fragments from LDS instead of 64 VGPRs.
// Evidence: 7 variants pinned at ~43us with occupancy 23% (2 waves/SIMD);
// the register working set (~160, w1f=64 of it) sits past the 2-wave cliff
// and every non-register poke was null; R20 proved occupancy moves when the
// set shrinks but recompute tax ate the gain. w1frag's layout makes each
// A-frag read a single ds_read_b128 with a 16-bit offset immediate (zero
// VALU addr math, loop-invariant base = lane*16). Freed 64+16 regs (also
// dropped R21's null hlreg rotate) -> ~90 regs -> launch_bounds(256,4),
// 4 waves/SIMD. LDS 38.1 KB -> 4 blocks/CU. Values and op order unchanged
// -> bitwise identical (absmax must stay exactly 0.03125).
// prep / gemm_sig byte-identical to R21.

typedef _Float16 half8 __attribute__((ext_vector_type(8)));
typedef float floatx4 __attribute__((ext_vector_type(4)));
typedef float floatx2 __attribute__((ext_vector_type(2)));

union U4H8 { uint4 u; half8 h; };
union PKH8 { uint4 u; _Float16 h[8]; };
union PKH4 { uint2 u; _Float16 h[4]; };

// ---------------------------------------------------------------- prep
// blocks 0..2047: hlhr (fp16): seg0 HL_chg(+b0c), seg1 HR_chg,
//                 seg2 HL_dg(+b0d), seg3 HR_dg; each [1024][128]
// blocks 2048..2111: w1frag[br][f=mt*4+ks][lane][j] =
//                 f16( W1[ks*32+(lane>>4)*8+j][mt*16+(lane&15)] )  (A-layout of W1^T)
__global__ __launch_bounds__(256) void prep(
    const float* __restrict__ Xch, const float* __restrict__ Xg,
    const float* __restrict__ Xd,
    const float* __restrict__ Wc0, const float* __restrict__ bc0,
    const float* __restrict__ Wd0, const float* __restrict__ bd0,
    const float* __restrict__ W1c, const float* __restrict__ W1d,
    _Float16* __restrict__ hlhr, _Float16* __restrict__ w1frag)
{
    int bid = blockIdx.x;
    if (bid < 2048) {
        int t = bid * 256 + threadIdx.x;   // 524288 threads
        int seg = t >> 17;
        int i = (t >> 7) & 1023;
        int k = t & 127;
        const float* X;
        const float* W;
        float s = 0.f;
        int wo = 0;
        if (seg == 0)      { X = Xch; W = Wc0; s = bc0[k]; }
        else if (seg == 1) { X = Xg;  W = Wc0; wo = 5; }
        else if (seg == 2) { X = Xg;  W = Wd0; s = bd0[k]; }
        else               { X = Xd;  W = Wd0; wo = 5; }
#pragma unroll
        for (int j = 0; j < 5; ++j)
            s += X[i * 5 + j] * W[(wo + j) * 128 + k];
        hlhr[t] = (_Float16)s;   // fp32 dot, one RNE round to fp16
    } else {
        int t = (bid - 2048) * 256 + threadIdx.x;   // 16384 threads
        int br   = t >> 13;
        int f    = (t >> 9) & 15;
        int lane = (t >> 3) & 63;
        int j    = t & 7;
        int mt = f >> 2, ks = f & 3;
        int row = ks * 32 + (lane >> 4) * 8 + j;    // k of W1
        int col = mt * 16 + (lane & 15);            // n of W1
        const float* W = br ? W1d : W1c;
        w1frag[t] = (_Float16)W[row * 64 + col];
    }
}

// ---------------------------------------------------------------- branch
#define LC 16          // l-values per block
#define PSTRIDE 69     // part[] pair stride in floats: 4 quads * 17 + 1

__global__ __launch_bounds__(256, 4) void branch_kernel(
    const _Float16* __restrict__ hlhr,
    const float* __restrict__ b1_chg, const float* __restrict__ wr_chg, const float* __restrict__ br_chg,
    const float* __restrict__ b1_dg,  const float* __restrict__ wr_dg,  const float* __restrict__ br_dg,
    const _Float16* __restrict__ w1frag,
    float* __restrict__ d_out,
    _Float16* __restrict__ wsh)   // [0:1M) Achg f16 [ch][g], [1M:2M) AgdT f16 [d][g]
{
    __shared__ _Float16 hl_tile[LC * 128];        // 4 KB
    __shared__ _Float16 w1lds[8192];              // 16 KB: this branch's W1 A-frags
    __shared__ float part[64 * PSTRIDE];          // per-quad y partials (17.7 KB)

    const int bz = blockIdx.z;
    const _Float16* HL = hlhr + (bz ? 262144 : 0);
    const _Float16* HR = hlhr + (bz ? 393216 : 131072);
    const float* b1 = bz ? b1_dg : b1_chg;
    const float* wr = bz ? wr_dg : wr_chg;
    const float brv = bz ? br_dg[0] : br_chg[0];
    float* outA = d_out + (bz ? 2097152 : 1048576);
    _Float16* outB = wsh + (bz ? 1048576 : 0);

    const int tid = threadIdx.x;
    const int lane = tid & 63, wave = tid >> 6;
    const int m = lane & 15, quad = lane >> 4;
    const int lbase = blockIdx.y * LC;
    const int rbase = blockIdx.x * 64;
    const int rm = rbase + wave * 16 + m;   // this lane's pair (column)
    const int p = wave * 16 + m;            // pair index within block

    {   // stage hl tile (fp16): LC*128 halves = 256 uint4
        const uint4* src = (const uint4*)(HL + lbase * 128);
        uint4* dst = (uint4*)hl_tile;
        dst[tid] = src[tid];
    }
    {   // stage W1 A-frags: 8192 halves = 1024 uint4 (layout (f*64+lane)*8)
        const uint4* src = (const uint4*)(w1frag + bz * 8192);
        uint4* dst = (uint4*)w1lds;
#pragma unroll
        for (int i = 0; i < 4; ++i)
            dst[tid + i * 256] = src[tid + i * 256];
    }

    // hr in B-frag k-order (fp16): k = ks*32 + quad*8 + j
    half8 hr16[4];
#pragma unroll
    for (int ks = 0; ks < 4; ++ks)
        hr16[ks] = *(const half8*)(HR + rm * 128 + ks * 32 + quad * 8);

    // per-lane n-slice constants: n = mt*16 + quad*4 + r
    floatx4 b1q[4], wr4[4];
#pragma unroll
    for (int mt = 0; mt < 4; ++mt) {
        b1q[mt] = *(const floatx4*)(b1 + mt * 16 + quad * 4);
        wr4[mt] = *(const floatx4*)(wr + mt * 16 + quad * 4);
    }

    const floatx4 z4 = (floatx4){0.f, 0.f, 0.f, 0.f};
    half8 hz;
#pragma unroll
    for (int j = 0; j < 8; ++j) hz[j] = (_Float16)0.f;

    __syncthreads();

    // A-frag reads: base = lane*16 bytes, per-frag 16-bit offset immediate
    // -> single ds_read_b128 each, no VALU address math.
    const uint4* w1p = (const uint4*)w1lds;
    float* pbase = part + p * PSTRIDE + quad * 17;

#pragma unroll 1
    for (int li = 0; li < LC; ++li) {
        const _Float16* hlp = hl_tile + li * 128;

        // h = relu(hl16 + hr16) in packed fp16 -> B-fragments
        half8 bfr[4];
#pragma unroll
        for (int ks = 0; ks < 4; ++ks) {
            half8 hl8 = *(const half8*)(hlp + ks * 32 + quad * 8);
            bfr[ks] = __builtin_elementwise_max(hl8 + hr16[ks], hz);
        }

        // b1 folded into the FIRST MFMA's C operand; A-frags from LDS.
        floatx4 acc[4];
#pragma unroll
        for (int mt = 0; mt < 4; ++mt) {
            U4H8 a; a.u = w1p[(mt * 4 + 0) * 64 + lane];
            acc[mt] = __builtin_amdgcn_mfma_f32_16x16x32_f16(a.h, bfr[0], b1q[mt], 0, 0, 0);
        }
#pragma unroll
        for (int ks = 1; ks < 4; ++ks)
#pragma unroll
            for (int mt = 0; mt < 4; ++mt) {
                U4H8 a; a.u = w1p[(mt * 4 + ks) * 64 + lane];
                acc[mt] = __builtin_amdgcn_mfma_f32_16x16x32_f16(a.h, bfr[ks], acc[mt], 0, 0, 0);
            }

        // acc[mt][r] = h1[pair rm][n = mt*16+quad*4+r] + b1;  dot with Wr.
        floatx4 y4 = z4;
#pragma unroll
        for (int mt = 0; mt < 4; ++mt)
            y4 += __builtin_elementwise_max(acc[mt], z4) * wr4[mt];
        float y = (y4[0] + y4[1]) + (y4[2] + y4[3]);

        // quad partial; cross-quad reduction deferred to epilogue.
        pbase[li] = y;
    }

    __syncthreads();

    // ---- epilogue pass 1: [li][pp] order -> outA (both) + outB (bz==0)
    {
        int li = tid >> 4;            // 0..15
        int p0 = (tid & 15) * 4;      // 0,4,..,60
        float v[4];
#pragma unroll
        for (int j = 0; j < 4; ++j) {
            const float* q = part + (p0 + j) * PSTRIDE + li;
            float yv = ((q[0] + q[17]) + (q[34] + q[51])) + brv;
            v[j] = yv > 0.f ? yv : (__expf(yv) - 1.f);   // elu
        }
        *(float4*)(outA + (lbase + li) * 1024 + rbase + p0) =
            make_float4(v[0], v[1], v[2], v[3]);
        if (bz == 0) {
            PKH4 pk;
#pragma unroll
            for (int j = 0; j < 4; ++j) pk.h[j] = (_Float16)v[j];
            *(uint2*)(outB + (lbase + li) * 1024 + rbase + p0) = pk.u;
        }
    }
    // ---- epilogue pass 2 (bz==1): [pp][li] order -> AgdT transposed
    if (bz == 1) {
        int pp = tid >> 2;            // 0..63
        int li0 = (tid & 3) * 4;      // 0,4,8,12
        PKH4 pk;
#pragma unroll
        for (int j = 0; j < 4; ++j) {
            const float* q = part + pp * PSTRIDE + li0 + j;
            float yv = ((q[0] + q[17]) + (q[34] + q[51])) + brv;
            float v = yv > 0.f ? yv : (__expf(yv) - 1.f);
            pk.h[j] = (_Float16)v;
        }
        *(uint2*)(outB + (rbase + pp) * 1024 + lbase + li0) = pk.u;
    }
}

// ---------------------------------------------------------------- final GEMM + sigmoid
// C[ch][d] = sum_g Achg[ch][g]*Agd[g][d]; fp16 MFMA, fp32 accum.
// R18: 32x32 tiles, BK=128 -> 8 K-iterations, 16 barriers. Staging is
// 2 uint4/thread per matrix (16 VGPRs live across the barrier — small enough
// to never spill). Register prefetch issued right after the post-write
// barrier; 8 ds_read_b128 + 4 MFMAs per iteration. Even/odd global k-slice
// parity preserved in ascending order -> accumulation bitwise identical.
#define GSTR 136   // LDS row stride in halves (128 + 8 pad)

__global__ __launch_bounds__(256) void gemm_sig(
    const _Float16* __restrict__ Ahf,   // [1024][1024] ch x g
    const _Float16* __restrict__ BThf,  // [1024][1024] d x g
    float* __restrict__ out0)
{
    __shared__ _Float16 At[32 * GSTR];   // 8.7 KB
    __shared__ _Float16 Bt[32 * GSTR];   // 8.7 KB

    const int tid = threadIdx.x, lane = tid & 63, wave = tid >> 6;
    const int m = lane & 15, quad = lane >> 4;
    const int chbase = blockIdx.y * 32, dbase = blockIdx.x * 32;
    const int wrow = (wave >> 1) * 16, wcol = (wave & 1) * 16;

    floatx4 acc0 = (floatx4){0.f, 0.f, 0.f, 0.f};
    floatx4 acc1 = (floatx4){0.f, 0.f, 0.f, 0.f};

    // staging map: row = tid>>3 (0..31), c8 = tid&7; each thread covers
    // uint4 cols {c8, c8+8} of the 16-uint4 (128-half) row: 128B coalesced
    // segments per 8 lanes.
    const int row = tid >> 3, c8 = tid & 7;
    const _Float16* gA = Ahf + (chbase + row) * 1024 + c8 * 8;
    const _Float16* gB = BThf + (dbase + row) * 1024 + c8 * 8;

    uint4 ra0 = *(const uint4*)(gA);
    uint4 ra1 = *(const uint4*)(gA + 64);
    uint4 rb0 = *(const uint4*)(gB);
    uint4 rb1 = *(const uint4*)(gB + 64);

#pragma unroll
    for (int kb = 0; kb < 8; ++kb) {
        *(uint4*)(At + row * GSTR + c8 * 8) = ra0;
        *(uint4*)(At + row * GSTR + 64 + c8 * 8) = ra1;
        *(uint4*)(Bt + row * GSTR + c8 * 8) = rb0;
        *(uint4*)(Bt + row * GSTR + 64 + c8 * 8) = rb1;
        __syncthreads();

        // prefetch next K-block (latency hides under the MFMA phase)
        if (kb < 7) {
            ra0 = *(const uint4*)(gA + (kb + 1) * 128);
            ra1 = *(const uint4*)(gA + (kb + 1) * 128 + 64);
            rb0 = *(const uint4*)(gB + (kb + 1) * 128);
            rb1 = *(const uint4*)(gB + (kb + 1) * 128 + 64);
        }

        // 4 k-slices of K=32; global slice s = kb*4+ks. Even s -> acc0,
        // odd s -> acc1, ascending -> bitwise identical to the BK=64 loop.
#pragma unroll
        for (int ks = 0; ks < 4; ks += 2) {
            half8 a0 = *(const half8*)(At + (wrow + m) * GSTR + ks * 32 + quad * 8);
            half8 b0 = *(const half8*)(Bt + (wcol + m) * GSTR + ks * 32 + quad * 8);
            half8 a1 = *(const half8*)(At + (wrow + m) * GSTR + (ks + 1) * 32 + quad * 8);
            half8 b1 = *(const half8*)(Bt + (wcol + m) * GSTR + (ks + 1) * 32 + quad * 8);
            acc0 = __builtin_amdgcn_mfma_f32_16x16x32_f16(a0, b0, acc0, 0, 0, 0);
            acc1 = __builtin_amdgcn_mfma_f32_16x16x32_f16(a1, b1, acc1, 0, 0, 0);
        }
        __syncthreads();
    }

    floatx4 acc = acc0 + acc1;
#pragma unroll
    for (int r = 0; r < 4; ++r) {
        int row_o = chbase + wrow + quad * 4 + r;
        int col_o = dbase + wcol + m;
        // sigmoid via fast exp + hw rcp (~1e-7 abs drift, well under tolerance)
        float e = __expf(-acc[r]);
        out0[row_o * 1024 + col_o] = __builtin_amdgcn_rcpf(1.f + e);
    }
}

// ---------------------------------------------------------------- launch
extern "C" void kernel_launch(void* const* d_in, const int* in_sizes, int n_in,
                              void* d_out, int out_size, void* d_ws, size_t ws_size,
                              hipStream_t stream) {
    const float* Xch = (const float*)d_in[0];
    const float* Xg  = (const float*)d_in[1];
    const float* Xd  = (const float*)d_in[2];
    const float* Wc0 = (const float*)d_in[3];
    const float* bc0 = (const float*)d_in[4];
    const float* Wc1 = (const float*)d_in[5];
    const float* bc1 = (const float*)d_in[6];
    const float* Wcr = (const float*)d_in[7];
    const float* bcr = (const float*)d_in[8];
    const float* Wd0 = (const float*)d_in[9];
    const float* bd0 = (const float*)d_in[10];
    const float* Wd1 = (const float*)d_in[11];
    const float* bd1 = (const float*)d_in[12];
    const float* Wdr = (const float*)d_in[13];
    const float* bdr = (const float*)d_in[14];

    float* out = (float*)d_out;
    _Float16* hlhr = (_Float16*)d_ws;            // 4x1024x128 fp16 = 1 MB
    _Float16* wsh = hlhr + 524288;               // Achg f16 1M + AgdT f16 1M
    _Float16* w1frag = wsh + 2097152;            // 16384 f16

    prep<<<2112, 256, 0, stream>>>(Xch, Xg, Xd, Wc0, bc0, Wd0, bd0, Wc1, Wd1,
                                   hlhr, w1frag);

    dim3 gb(16, 64, 2);   // (r-chunks of 64, l-chunks of 16, branch)
    branch_kernel<<<gb, 256, 0, stream>>>(hlhr, bc1, Wcr, bcr, bd1, Wdr, bdr,
                                          w1frag, out, wsh);

    dim3 gg(32, 32);
    gemm_sig<<<gg, 256, 0, stream>>>(wsh, wsh + 1048576, out);
}

// Round 10
// 134.167 us; speedup vs baseline: 1.1408x; 1.1408x over previous
//
#include <hip/hip_runtime.h>
#include <hip/hip_bf16.h>

// Two pairwise MLPs (ChG, DG) over 1024x1024 pairs, then A_chg @ A_gd, sigmoid.
// Outputs concat: [0:1M) sigmoid(A_chd), [1M:2M) A_chg, [2M:3M) A_gd (fp32).
//
// R23 = R19 branch with the bfr array folded to one half8 (live-range shave).
// Evidence chain: R22 (w1f->LDS) freed regs and occupancy jumped 23->38% but
// went LDS-throughput-bound (20 b128/wave-li > CU LDS budget) -> 68us. R19's
// (256,3) failed to reach 3 waves because the combined VGPR+AGPR set was
// ~175, just over the 170 cap: w1f 64 + hr16 16 + b1q 16 + wr4 16 + acc 16 +
// bfr 16 + temps. R23 computes bfr per-ks right before its 4 MFMAs (live
// ranges don't overlap, ~12 regs freed -> ~160 <= 170 -> 3 waves/SIMD).
// The per-ks bfr VALU issues under the previous ks's MFMA chains. Values and
// op order unchanged -> bitwise identical (absmax exactly 0.03125).
// prep / gemm_sig byte-identical to R18-R22 (proven best).

typedef _Float16 half8 __attribute__((ext_vector_type(8)));
typedef float floatx4 __attribute__((ext_vector_type(4)));
typedef float floatx2 __attribute__((ext_vector_type(2)));

union U4H8 { uint4 u; half8 h; };
union PKH8 { uint4 u; _Float16 h[8]; };
union PKH4 { uint2 u; _Float16 h[4]; };

// ---------------------------------------------------------------- prep
// blocks 0..2047: hlhr (fp16): seg0 HL_chg(+b0c), seg1 HR_chg,
//                 seg2 HL_dg(+b0d), seg3 HR_dg; each [1024][128]
// blocks 2048..2111: w1frag[br][f=mt*4+ks][lane][j] =
//                 f16( W1[ks*32+(lane>>4)*8+j][mt*16+(lane&15)] )  (A-layout of W1^T)
__global__ __launch_bounds__(256) void prep(
    const float* __restrict__ Xch, const float* __restrict__ Xg,
    const float* __restrict__ Xd,
    const float* __restrict__ Wc0, const float* __restrict__ bc0,
    const float* __restrict__ Wd0, const float* __restrict__ bd0,
    const float* __restrict__ W1c, const float* __restrict__ W1d,
    _Float16* __restrict__ hlhr, _Float16* __restrict__ w1frag)
{
    int bid = blockIdx.x;
    if (bid < 2048) {
        int t = bid * 256 + threadIdx.x;   // 524288 threads
        int seg = t >> 17;
        int i = (t >> 7) & 1023;
        int k = t & 127;
        const float* X;
        const float* W;
        float s = 0.f;
        int wo = 0;
        if (seg == 0)      { X = Xch; W = Wc0; s = bc0[k]; }
        else if (seg == 1) { X = Xg;  W = Wc0; wo = 5; }
        else if (seg == 2) { X = Xg;  W = Wd0; s = bd0[k]; }
        else               { X = Xd;  W = Wd0; wo = 5; }
#pragma unroll
        for (int j = 0; j < 5; ++j)
            s += X[i * 5 + j] * W[(wo + j) * 128 + k];
        hlhr[t] = (_Float16)s;   // fp32 dot, one RNE round to fp16
    } else {
        int t = (bid - 2048) * 256 + threadIdx.x;   // 16384 threads
        int br   = t >> 13;
        int f    = (t >> 9) & 15;
        int lane = (t >> 3) & 63;
        int j    = t & 7;
        int mt = f >> 2, ks = f & 3;
        int row = ks * 32 + (lane >> 4) * 8 + j;    // k of W1
        int col = mt * 16 + (lane & 15);            // n of W1
        const float* W = br ? W1d : W1c;
        w1frag[t] = (_Float16)W[row * 64 + col];
    }
}

// ---------------------------------------------------------------- branch
#define LC 16          // l-values per block
#define PSTRIDE 69     // part[] pair stride in floats: 4 quads * 17 + 1

__global__ __launch_bounds__(256, 3) void branch_kernel(
    const _Float16* __restrict__ hlhr,
    const float* __restrict__ b1_chg, const float* __restrict__ wr_chg, const float* __restrict__ br_chg,
    const float* __restrict__ b1_dg,  const float* __restrict__ wr_dg,  const float* __restrict__ br_dg,
    const _Float16* __restrict__ w1frag,
    float* __restrict__ d_out,
    _Float16* __restrict__ wsh)   // [0:1M) Achg f16 [ch][g], [1M:2M) AgdT f16 [d][g]
{
    __shared__ _Float16 hl_tile[LC * 128];        // 4 KB
    __shared__ float part[64 * PSTRIDE];          // per-quad y partials [p][q*17+li] (17.7 KB)

    const int bz = blockIdx.z;
    const _Float16* HL = hlhr + (bz ? 262144 : 0);
    const _Float16* HR = hlhr + (bz ? 393216 : 131072);
    const float* b1 = bz ? b1_dg : b1_chg;
    const float* wr = bz ? wr_dg : wr_chg;
    const float brv = bz ? br_dg[0] : br_chg[0];
    float* outA = d_out + (bz ? 2097152 : 1048576);
    _Float16* outB = wsh + (bz ? 1048576 : 0);

    const int tid = threadIdx.x;
    const int lane = tid & 63, wave = tid >> 6;
    const int m = lane & 15, quad = lane >> 4;
    const int lbase = blockIdx.y * LC;
    const int rbase = blockIdx.x * 64;
    const int rm = rbase + wave * 16 + m;   // this lane's pair (column)
    const int p = wave * 16 + m;            // pair index within block

    {   // stage hl tile (fp16): LC*128 halves = 256 uint4
        const uint4* src = (const uint4*)(HL + lbase * 128);
        uint4* dst = (uint4*)hl_tile;
        dst[tid] = src[tid];
    }

    // hr in B-frag k-order (fp16): k = ks*32 + quad*8 + j
    half8 hr16[4];
#pragma unroll
    for (int ks = 0; ks < 4; ++ks)
        hr16[ks] = *(const half8*)(HR + rm * 128 + ks * 32 + quad * 8);

    // W1^T A-fragments (constant across the loop)
    half8 w1f[4][4];   // [mt][ks]
    {
        const uint4* wf = (const uint4*)(w1frag + bz * 8192);
#pragma unroll
        for (int f = 0; f < 16; ++f) {
            U4H8 t; t.u = wf[f * 64 + lane];
            w1f[f >> 2][f & 3] = t.h;
        }
    }

    // per-lane n-slice constants: n = mt*16 + quad*4 + r
    floatx4 b1q[4], wr4[4];
#pragma unroll
    for (int mt = 0; mt < 4; ++mt) {
        b1q[mt] = *(const floatx4*)(b1 + mt * 16 + quad * 4);
        wr4[mt] = *(const floatx4*)(wr + mt * 16 + quad * 4);
    }

    const floatx4 z4 = (floatx4){0.f, 0.f, 0.f, 0.f};
    half8 hz;
#pragma unroll
    for (int j = 0; j < 8; ++j) hz[j] = (_Float16)0.f;

    __syncthreads();

    float* pbase = part + p * PSTRIDE + quad * 17;

#pragma unroll 1
    for (int li = 0; li < LC; ++li) {
        const _Float16* hlp = hl_tile + li * 128;
        floatx4 acc[4];

        // ks = 0: bfr computed immediately before its 4 MFMAs (single live
        // half8, not a 16-reg array); b1 folded into the C operand.
        {
            half8 hl8 = *(const half8*)(hlp + quad * 8);
            half8 bfr = __builtin_elementwise_max(hl8 + hr16[0], hz);
#pragma unroll
            for (int mt = 0; mt < 4; ++mt)
                acc[mt] = __builtin_amdgcn_mfma_f32_16x16x32_f16(w1f[mt][0], bfr, b1q[mt], 0, 0, 0);
        }
#pragma unroll
        for (int ks = 1; ks < 4; ++ks) {
            half8 hl8 = *(const half8*)(hlp + ks * 32 + quad * 8);
            half8 bfr = __builtin_elementwise_max(hl8 + hr16[ks], hz);
#pragma unroll
            for (int mt = 0; mt < 4; ++mt)
                acc[mt] = __builtin_amdgcn_mfma_f32_16x16x32_f16(w1f[mt][ks], bfr, acc[mt], 0, 0, 0);
        }

        // acc[mt][r] = h1[pair rm][n = mt*16+quad*4+r] + b1;  dot with Wr.
        floatx4 y4 = z4;
#pragma unroll
        for (int mt = 0; mt < 4; ++mt)
            y4 += __builtin_elementwise_max(acc[mt], z4) * wr4[mt];
        float y = (y4[0] + y4[1]) + (y4[2] + y4[3]);

        // quad partial; cross-quad reduction deferred to epilogue.
        pbase[li] = y;
    }

    __syncthreads();

    // ---- epilogue pass 1: [li][pp] order -> outA (both) + outB (bz==0)
    {
        int li = tid >> 4;            // 0..15
        int p0 = (tid & 15) * 4;      // 0,4,..,60
        float v[4];
#pragma unroll
        for (int j = 0; j < 4; ++j) {
            const float* q = part + (p0 + j) * PSTRIDE + li;
            float yv = ((q[0] + q[17]) + (q[34] + q[51])) + brv;
            v[j] = yv > 0.f ? yv : (__expf(yv) - 1.f);   // elu
        }
        *(float4*)(outA + (lbase + li) * 1024 + rbase + p0) =
            make_float4(v[0], v[1], v[2], v[3]);
        if (bz == 0) {
            PKH4 pk;
#pragma unroll
            for (int j = 0; j < 4; ++j) pk.h[j] = (_Float16)v[j];
            *(uint2*)(outB + (lbase + li) * 1024 + rbase + p0) = pk.u;
        }
    }
    // ---- epilogue pass 2 (bz==1): [pp][li] order -> AgdT transposed
    if (bz == 1) {
        int pp = tid >> 2;            // 0..63
        int li0 = (tid & 3) * 4;      // 0,4,8,12
        PKH4 pk;
#pragma unroll
        for (int j = 0; j < 4; ++j) {
            const float* q = part + pp * PSTRIDE + li0 + j;
            float yv = ((q[0] + q[17]) + (q[34] + q[51])) + brv;
            float v = yv > 0.f ? yv : (__expf(yv) - 1.f);
            pk.h[j] = (_Float16)v;
        }
        *(uint2*)(outB + (rbase + pp) * 1024 + lbase + li0) = pk.u;
    }
}

// ---------------------------------------------------------------- final GEMM + sigmoid
// C[ch][d] = sum_g Achg[ch][g]*Agd[g][d]; fp16 MFMA, fp32 accum.
// R18: 32x32 tiles, BK=128 -> 8 K-iterations, 16 barriers. Staging is
// 2 uint4/thread per matrix (16 VGPRs live across the barrier — small enough
// to never spill). Register prefetch issued right after the post-write
// barrier; 8 ds_read_b128 + 4 MFMAs per iteration. Even/odd global k-slice
// parity preserved in ascending order -> accumulation bitwise identical.
#define GSTR 136   // LDS row stride in halves (128 + 8 pad)

__global__ __launch_bounds__(256) void gemm_sig(
    const _Float16* __restrict__ Ahf,   // [1024][1024] ch x g
    const _Float16* __restrict__ BThf,  // [1024][1024] d x g
    float* __restrict__ out0)
{
    __shared__ _Float16 At[32 * GSTR];   // 8.7 KB
    __shared__ _Float16 Bt[32 * GSTR];   // 8.7 KB

    const int tid = threadIdx.x, lane = tid & 63, wave = tid >> 6;
    const int m = lane & 15, quad = lane >> 4;
    const int chbase = blockIdx.y * 32, dbase = blockIdx.x * 32;
    const int wrow = (wave >> 1) * 16, wcol = (wave & 1) * 16;

    floatx4 acc0 = (floatx4){0.f, 0.f, 0.f, 0.f};
    floatx4 acc1 = (floatx4){0.f, 0.f, 0.f, 0.f};

    // staging map: row = tid>>3 (0..31), c8 = tid&7; each thread covers
    // uint4 cols {c8, c8+8} of the 16-uint4 (128-half) row: 128B coalesced
    // segments per 8 lanes.
    const int row = tid >> 3, c8 = tid & 7;
    const _Float16* gA = Ahf + (chbase + row) * 1024 + c8 * 8;
    const _Float16* gB = BThf + (dbase + row) * 1024 + c8 * 8;

    uint4 ra0 = *(const uint4*)(gA);
    uint4 ra1 = *(const uint4*)(gA + 64);
    uint4 rb0 = *(const uint4*)(gB);
    uint4 rb1 = *(const uint4*)(gB + 64);

#pragma unroll
    for (int kb = 0; kb < 8; ++kb) {
        *(uint4*)(At + row * GSTR + c8 * 8) = ra0;
        *(uint4*)(At + row * GSTR + 64 + c8 * 8) = ra1;
        *(uint4*)(Bt + row * GSTR + c8 * 8) = rb0;
        *(uint4*)(Bt + row * GSTR + 64 + c8 * 8) = rb1;
        __syncthreads();

        // prefetch next K-block (latency hides under the MFMA phase)
        if (kb < 7) {
            ra0 = *(const uint4*)(gA + (kb + 1) * 128);
            ra1 = *(const uint4*)(gA + (kb + 1) * 128 + 64);
            rb0 = *(const uint4*)(gB + (kb + 1) * 128);
            rb1 = *(const uint4*)(gB + (kb + 1) * 128 + 64);
        }

        // 4 k-slices of K=32; global slice s = kb*4+ks. Even s -> acc0,
        // odd s -> acc1, ascending -> bitwise identical to the BK=64 loop.
#pragma unroll
        for (int ks = 0; ks < 4; ks += 2) {
            half8 a0 = *(const half8*)(At + (wrow + m) * GSTR + ks * 32 + quad * 8);
            half8 b0 = *(const half8*)(Bt + (wcol + m) * GSTR + ks * 32 + quad * 8);
            half8 a1 = *(const half8*)(At + (wrow + m) * GSTR + (ks + 1) * 32 + quad * 8);
            half8 b1 = *(const half8*)(Bt + (wcol + m) * GSTR + (ks + 1) * 32 + quad * 8);
            acc0 = __builtin_amdgcn_mfma_f32_16x16x32_f16(a0, b0, acc0, 0, 0, 0);
            acc1 = __builtin_amdgcn_mfma_f32_16x16x32_f16(a1, b1, acc1, 0, 0, 0);
        }
        __syncthreads();
    }

    floatx4 acc = acc0 + acc1;
#pragma unroll
    for (int r = 0; r < 4; ++r) {
        int row_o = chbase + wrow + quad * 4 + r;
        int col_o = dbase + wcol + m;
        // sigmoid via fast exp + hw rcp (~1e-7 abs drift, well under tolerance)
        float e = __expf(-acc[r]);
        out0[row_o * 1024 + col_o] = __builtin_amdgcn_rcpf(1.f + e);
    }
}

// ---------------------------------------------------------------- launch
extern "C" void kernel_launch(void* const* d_in, const int* in_sizes, int n_in,
                              void* d_out, int out_size, void* d_ws, size_t ws_size,
                              hipStream_t stream) {
    const float* Xch = (const float*)d_in[0];
    const float* Xg  = (const float*)d_in[1];
    const float* Xd  = (const float*)d_in[2];
    const float* Wc0 = (const float*)d_in[3];
    const float* bc0 = (const float*)d_in[4];
    const float* Wc1 = (const float*)d_in[5];
    const float* bc1 = (const float*)d_in[6];
    const float* Wcr = (const float*)d_in[7];
    const float* bcr = (const float*)d_in[8];
    const float* Wd0 = (const float*)d_in[9];
    const float* bd0 = (const float*)d_in[10];
    const float* Wd1 = (const float*)d_in[11];
    const float* bd1 = (const float*)d_in[12];
    const float* Wdr = (const float*)d_in[13];
    const float* bdr = (const float*)d_in[14];

    float* out = (float*)d_out;
    _Float16* hlhr = (_Float16*)d_ws;            // 4x1024x128 fp16 = 1 MB
    _Float16* wsh = hlhr + 524288;               // Achg f16 1M + AgdT f16 1M
    _Float16* w1frag = wsh + 2097152;            // 16384 f16

    prep<<<2112, 256, 0, stream>>>(Xch, Xg, Xd, Wc0, bc0, Wd0, bd0, Wc1, Wd1,
                                   hlhr, w1frag);

    dim3 gb(16, 64, 2);   // (r-chunks of 64, l-chunks of 16, branch)
    branch_kernel<<<gb, 256, 0, stream>>>(hlhr, bc1, Wcr, bcr, bd1, Wdr, bdr,
                                          w1frag, out, wsh);

    dim3 gg(32, 32);
    gemm_sig<<<gg, 256, 0, stream>>>(wsh, wsh + 1048576, out);
}

// Round 11
// 131.674 us; speedup vs baseline: 1.1624x; 1.0189x over previous
//
#include <hip/hip_runtime.h>
#include <hip/hip_bf16.h>

// Two pairwise MLPs (ChG, DG) over 1024x1024 pairs, then A_chg @ A_gd, sigmoid.
// Outputs concat: [0:1M) sigmoid(A_chd), [1M:2M) A_chg, [2M:3M) A_gd (fp32).
//
// R24 = exact R18 base (best measured, 129.8us) + two zero-numeric-risk adds:
//   (a) gemm_sig LDS double-buffer: 1 barrier/K-iter instead of 2 (8 vs 16
//       drains). gemm at 13.6us vs ~1us MFMA is barrier-bound. Write goes to
//       the opposite buffer from all in-flight reads; __syncthreads' waitcnt
//       covers the 2-iter-apart reuse. Values/order identical.
//   (b) branch s_setprio(1) around the MFMA cluster (T5): branch's li loop is
//       barrier-free -> waves drift (the attn-like regime where setprio paid
//       +4-7%, m191), unlike lockstep GEMM (m190 null).
// Branch register thread closed: R20/R22 moved occupancy (23->32/38%) but
// paid more in added work; 9 variants pin branch at ~43us = 2.2x its MFMA
// floor. prep byte-identical. absmax must stay exactly 0.03125.

typedef _Float16 half8 __attribute__((ext_vector_type(8)));
typedef float floatx4 __attribute__((ext_vector_type(4)));
typedef float floatx2 __attribute__((ext_vector_type(2)));

union U4H8 { uint4 u; half8 h; };
union PKH8 { uint4 u; _Float16 h[8]; };
union PKH4 { uint2 u; _Float16 h[4]; };

// ---------------------------------------------------------------- prep
// blocks 0..2047: hlhr (fp16): seg0 HL_chg(+b0c), seg1 HR_chg,
//                 seg2 HL_dg(+b0d), seg3 HR_dg; each [1024][128]
// blocks 2048..2111: w1frag[br][f=mt*4+ks][lane][j] =
//                 f16( W1[ks*32+(lane>>4)*8+j][mt*16+(lane&15)] )  (A-layout of W1^T)
__global__ __launch_bounds__(256) void prep(
    const float* __restrict__ Xch, const float* __restrict__ Xg,
    const float* __restrict__ Xd,
    const float* __restrict__ Wc0, const float* __restrict__ bc0,
    const float* __restrict__ Wd0, const float* __restrict__ bd0,
    const float* __restrict__ W1c, const float* __restrict__ W1d,
    _Float16* __restrict__ hlhr, _Float16* __restrict__ w1frag)
{
    int bid = blockIdx.x;
    if (bid < 2048) {
        int t = bid * 256 + threadIdx.x;   // 524288 threads
        int seg = t >> 17;
        int i = (t >> 7) & 1023;
        int k = t & 127;
        const float* X;
        const float* W;
        float s = 0.f;
        int wo = 0;
        if (seg == 0)      { X = Xch; W = Wc0; s = bc0[k]; }
        else if (seg == 1) { X = Xg;  W = Wc0; wo = 5; }
        else if (seg == 2) { X = Xg;  W = Wd0; s = bd0[k]; }
        else               { X = Xd;  W = Wd0; wo = 5; }
#pragma unroll
        for (int j = 0; j < 5; ++j)
            s += X[i * 5 + j] * W[(wo + j) * 128 + k];
        hlhr[t] = (_Float16)s;   // fp32 dot, one RNE round to fp16
    } else {
        int t = (bid - 2048) * 256 + threadIdx.x;   // 16384 threads
        int br   = t >> 13;
        int f    = (t >> 9) & 15;
        int lane = (t >> 3) & 63;
        int j    = t & 7;
        int mt = f >> 2, ks = f & 3;
        int row = ks * 32 + (lane >> 4) * 8 + j;    // k of W1
        int col = mt * 16 + (lane & 15);            // n of W1
        const float* W = br ? W1d : W1c;
        w1frag[t] = (_Float16)W[row * 64 + col];
    }
}

// ---------------------------------------------------------------- branch
#define LC 16          // l-values per block
#define PSTRIDE 69     // part[] pair stride in floats: 4 quads * 17 + 1

__global__ __launch_bounds__(256, 2) void branch_kernel(
    const _Float16* __restrict__ hlhr,
    const float* __restrict__ b1_chg, const float* __restrict__ wr_chg, const float* __restrict__ br_chg,
    const float* __restrict__ b1_dg,  const float* __restrict__ wr_dg,  const float* __restrict__ br_dg,
    const _Float16* __restrict__ w1frag,
    float* __restrict__ d_out,
    _Float16* __restrict__ wsh)   // [0:1M) Achg f16 [ch][g], [1M:2M) AgdT f16 [d][g]
{
    __shared__ _Float16 hl_tile[LC * 128];        // 4 KB
    __shared__ float part[64 * PSTRIDE];          // per-quad y partials [p][q*17+li] (17.7 KB)

    const int bz = blockIdx.z;
    const _Float16* HL = hlhr + (bz ? 262144 : 0);
    const _Float16* HR = hlhr + (bz ? 393216 : 131072);
    const float* b1 = bz ? b1_dg : b1_chg;
    const float* wr = bz ? wr_dg : wr_chg;
    const float brv = bz ? br_dg[0] : br_chg[0];
    float* outA = d_out + (bz ? 2097152 : 1048576);
    _Float16* outB = wsh + (bz ? 1048576 : 0);

    const int tid = threadIdx.x;
    const int lane = tid & 63, wave = tid >> 6;
    const int m = lane & 15, quad = lane >> 4;
    const int lbase = blockIdx.y * LC;
    const int rbase = blockIdx.x * 64;
    const int rm = rbase + wave * 16 + m;   // this lane's pair (column)
    const int p = wave * 16 + m;            // pair index within block

    {   // stage hl tile (fp16): LC*128 halves = 256 uint4
        const uint4* src = (const uint4*)(HL + lbase * 128);
        uint4* dst = (uint4*)hl_tile;
        dst[tid] = src[tid];
    }

    // hr in B-frag k-order (fp16): k = ks*32 + quad*8 + j
    half8 hr16[4];
#pragma unroll
    for (int ks = 0; ks < 4; ++ks)
        hr16[ks] = *(const half8*)(HR + rm * 128 + ks * 32 + quad * 8);

    // W1^T A-fragments (constant across the loop)
    half8 w1f[4][4];   // [mt][ks]
    {
        const uint4* wf = (const uint4*)(w1frag + bz * 8192);
#pragma unroll
        for (int f = 0; f < 16; ++f) {
            U4H8 t; t.u = wf[f * 64 + lane];
            w1f[f >> 2][f & 3] = t.h;
        }
    }

    // per-lane n-slice constants: n = mt*16 + quad*4 + r
    floatx4 b1q[4], wr4[4];
#pragma unroll
    for (int mt = 0; mt < 4; ++mt) {
        b1q[mt] = *(const floatx4*)(b1 + mt * 16 + quad * 4);
        wr4[mt] = *(const floatx4*)(wr + mt * 16 + quad * 4);
    }

    const floatx4 z4 = (floatx4){0.f, 0.f, 0.f, 0.f};
    half8 hz;
#pragma unroll
    for (int j = 0; j < 8; ++j) hz[j] = (_Float16)0.f;

    __syncthreads();

#pragma unroll 2
    for (int li = 0; li < LC; ++li) {
        const _Float16* hlp = hl_tile + li * 128;

        // h = relu(hl16 + hr16) in packed fp16 -> B-fragments
        half8 bfr[4];
#pragma unroll
        for (int ks = 0; ks < 4; ++ks) {
            half8 hl8 = *(const half8*)(hlp + ks * 32 + quad * 8);
            bfr[ks] = __builtin_elementwise_max(hl8 + hr16[ks], hz);
        }

        // b1 folded into the FIRST MFMA's C operand; setprio favors this
        // wave while its MFMA burst runs (waves drift -> arbitration helps).
        __builtin_amdgcn_s_setprio(1);
        floatx4 acc[4];
#pragma unroll
        for (int mt = 0; mt < 4; ++mt)
            acc[mt] = __builtin_amdgcn_mfma_f32_16x16x32_f16(w1f[mt][0], bfr[0], b1q[mt], 0, 0, 0);
#pragma unroll
        for (int ks = 1; ks < 4; ++ks)
#pragma unroll
            for (int mt = 0; mt < 4; ++mt)
                acc[mt] = __builtin_amdgcn_mfma_f32_16x16x32_f16(w1f[mt][ks], bfr[ks], acc[mt], 0, 0, 0);
        __builtin_amdgcn_s_setprio(0);

        // acc[mt][r] = h1[pair rm][n = mt*16+quad*4+r] + b1;  dot with Wr.
        floatx4 y4 = z4;
#pragma unroll
        for (int mt = 0; mt < 4; ++mt)
            y4 += __builtin_elementwise_max(acc[mt], z4) * wr4[mt];
        float y = (y4[0] + y4[1]) + (y4[2] + y4[3]);

        // quad partial; cross-quad reduction deferred to epilogue.
        part[p * PSTRIDE + quad * 17 + li] = y;
    }

    __syncthreads();

    // ---- epilogue pass 1: [li][pp] order -> outA (both) + outB (bz==0)
    {
        int li = tid >> 4;            // 0..15
        int p0 = (tid & 15) * 4;      // 0,4,..,60
        float v[4];
#pragma unroll
        for (int j = 0; j < 4; ++j) {
            const float* q = part + (p0 + j) * PSTRIDE + li;
            float yv = ((q[0] + q[17]) + (q[34] + q[51])) + brv;
            v[j] = yv > 0.f ? yv : (__expf(yv) - 1.f);   // elu
        }
        *(float4*)(outA + (lbase + li) * 1024 + rbase + p0) =
            make_float4(v[0], v[1], v[2], v[3]);
        if (bz == 0) {
            PKH4 pk;
#pragma unroll
            for (int j = 0; j < 4; ++j) pk.h[j] = (_Float16)v[j];
            *(uint2*)(outB + (lbase + li) * 1024 + rbase + p0) = pk.u;
        }
    }
    // ---- epilogue pass 2 (bz==1): [pp][li] order -> AgdT transposed
    if (bz == 1) {
        int pp = tid >> 2;            // 0..63
        int li0 = (tid & 3) * 4;      // 0,4,8,12
        PKH4 pk;
#pragma unroll
        for (int j = 0; j < 4; ++j) {
            const float* q = part + pp * PSTRIDE + li0 + j;
            float yv = ((q[0] + q[17]) + (q[34] + q[51])) + brv;
            float v = yv > 0.f ? yv : (__expf(yv) - 1.f);
            pk.h[j] = (_Float16)v;
        }
        *(uint2*)(outB + (rbase + pp) * 1024 + lbase + li0) = pk.u;
    }
}

// ---------------------------------------------------------------- final GEMM + sigmoid
// C[ch][d] = sum_g Achg[ch][g]*Agd[g][d]; fp16 MFMA, fp32 accum.
// R24: BK=128 double-buffered LDS -> ONE barrier per K-iter (8 vs 16 drains).
// Loop: write buf[cur] (staged regs) -> barrier -> prefetch kb+1 -> MFMA from
// buf[cur]. Writes always target the opposite buffer from any in-flight
// reads; __syncthreads' implicit waitcnt drains reads before reuse 2 iters
// later. Even/odd k-slice dual-acc ascending -> accumulation bitwise
// identical to R18/R16/R9.
#define GSTR 136   // LDS row stride in halves (128 + 8 pad)

__global__ __launch_bounds__(256) void gemm_sig(
    const _Float16* __restrict__ Ahf,   // [1024][1024] ch x g
    const _Float16* __restrict__ BThf,  // [1024][1024] d x g
    float* __restrict__ out0)
{
    __shared__ _Float16 At[2][32 * GSTR];   // 2 x 8.7 KB
    __shared__ _Float16 Bt[2][32 * GSTR];   // 2 x 8.7 KB

    const int tid = threadIdx.x, lane = tid & 63, wave = tid >> 6;
    const int m = lane & 15, quad = lane >> 4;
    const int chbase = blockIdx.y * 32, dbase = blockIdx.x * 32;
    const int wrow = (wave >> 1) * 16, wcol = (wave & 1) * 16;

    floatx4 acc0 = (floatx4){0.f, 0.f, 0.f, 0.f};
    floatx4 acc1 = (floatx4){0.f, 0.f, 0.f, 0.f};

    // staging map: row = tid>>3 (0..31), c8 = tid&7; each thread covers
    // uint4 cols {c8, c8+8} of the 16-uint4 (128-half) row.
    const int row = tid >> 3, c8 = tid & 7;
    const _Float16* gA = Ahf + (chbase + row) * 1024 + c8 * 8;
    const _Float16* gB = BThf + (dbase + row) * 1024 + c8 * 8;

    uint4 ra0 = *(const uint4*)(gA);
    uint4 ra1 = *(const uint4*)(gA + 64);
    uint4 rb0 = *(const uint4*)(gB);
    uint4 rb1 = *(const uint4*)(gB + 64);

#pragma unroll
    for (int kb = 0; kb < 8; ++kb) {
        const int cur = kb & 1;
        // write staged regs -> buf[cur] (nobody reads buf[cur] right now:
        // iter kb-1 read buf[cur^1]; reads of buf[cur] from iter kb-2 were
        // drained by the barrier below in iter kb-1).
        *(uint4*)(At[cur] + row * GSTR + c8 * 8) = ra0;
        *(uint4*)(At[cur] + row * GSTR + 64 + c8 * 8) = ra1;
        *(uint4*)(Bt[cur] + row * GSTR + c8 * 8) = rb0;
        *(uint4*)(Bt[cur] + row * GSTR + 64 + c8 * 8) = rb1;
        __syncthreads();   // writes visible; prior reads drained

        // prefetch next K-block (hides under the MFMA phase)
        if (kb < 7) {
            ra0 = *(const uint4*)(gA + (kb + 1) * 128);
            ra1 = *(const uint4*)(gA + (kb + 1) * 128 + 64);
            rb0 = *(const uint4*)(gB + (kb + 1) * 128);
            rb1 = *(const uint4*)(gB + (kb + 1) * 128 + 64);
        }

        // 4 k-slices of K=32; global slice s = kb*4+ks. Even s -> acc0,
        // odd s -> acc1, ascending -> bitwise identical accumulation.
#pragma unroll
        for (int ks = 0; ks < 4; ks += 2) {
            half8 a0 = *(const half8*)(At[cur] + (wrow + m) * GSTR + ks * 32 + quad * 8);
            half8 b0 = *(const half8*)(Bt[cur] + (wcol + m) * GSTR + ks * 32 + quad * 8);
            half8 a1 = *(const half8*)(At[cur] + (wrow + m) * GSTR + (ks + 1) * 32 + quad * 8);
            half8 b1 = *(const half8*)(Bt[cur] + (wcol + m) * GSTR + (ks + 1) * 32 + quad * 8);
            acc0 = __builtin_amdgcn_mfma_f32_16x16x32_f16(a0, b0, acc0, 0, 0, 0);
            acc1 = __builtin_amdgcn_mfma_f32_16x16x32_f16(a1, b1, acc1, 0, 0, 0);
        }
        // no second barrier: next iter writes buf[cur^1], untouched by the
        // ds_reads above; the next barrier drains them before buf[cur] reuse.
    }

    floatx4 acc = acc0 + acc1;
#pragma unroll
    for (int r = 0; r < 4; ++r) {
        int row_o = chbase + wrow + quad * 4 + r;
        int col_o = dbase + wcol + m;
        // sigmoid via fast exp + hw rcp (~1e-7 abs drift, well under tolerance)
        float e = __expf(-acc[r]);
        out0[row_o * 1024 + col_o] = __builtin_amdgcn_rcpf(1.f + e);
    }
}

// ---------------------------------------------------------------- launch
extern "C" void kernel_launch(void* const* d_in, const int* in_sizes, int n_in,
                              void* d_out, int out_size, void* d_ws, size_t ws_size,
                              hipStream_t stream) {
    const float* Xch = (const float*)d_in[0];
    const float* Xg  = (const float*)d_in[1];
    const float* Xd  = (const float*)d_in[2];
    const float* Wc0 = (const float*)d_in[3];
    const float* bc0 = (const float*)d_in[4];
    const float* Wc1 = (const float*)d_in[5];
    const float* bc1 = (const float*)d_in[6];
    const float* Wcr = (const float*)d_in[7];
    const float* bcr = (const float*)d_in[8];
    const float* Wd0 = (const float*)d_in[9];
    const float* bd0 = (const float*)d_in[10];
    const float* Wd1 = (const float*)d_in[11];
    const float* bd1 = (const float*)d_in[12];
    const float* Wdr = (const float*)d_in[13];
    const float* bdr = (const float*)d_in[14];

    float* out = (float*)d_out;
    _Float16* hlhr = (_Float16*)d_ws;            // 4x1024x128 fp16 = 1 MB
    _Float16* wsh = hlhr + 524288;               // Achg f16 1M + AgdT f16 1M
    _Float16* w1frag = wsh + 2097152;            // 16384 f16

    prep<<<2112, 256, 0, stream>>>(Xch, Xg, Xd, Wc0, bc0, Wd0, bd0, Wc1, Wd1,
                                   hlhr, w1frag);

    dim3 gb(16, 64, 2);   // (r-chunks of 64, l-chunks of 16, branch)
    branch_kernel<<<gb, 256, 0, stream>>>(hlhr, bc1, Wcr, bcr, bd1, Wdr, bdr,
                                          w1frag, out, wsh);

    dim3 gg(32, 32);
    gemm_sig<<<gg, 256, 0, stream>>>(wsh, wsh + 1048576, out);
}

// Round 12
// 128.794 us; speedup vs baseline: 1.1884x; 1.0224x over previous
//
#include <hip/hip_runtime.h>
#include <hip/hip_bf16.h>

// Two pairwise MLPs (ChG, DG) over 1024x1024 pairs, then A_chg @ A_gd, sigmoid.
// Outputs concat: [0:1M) sigmoid(A_chd), [1M:2M) A_chg, [2M:3M) A_gd (fp32).
//
// R25 = R18 (best measured, 129.8us) with gemm_sig retiled 32x32 -> 32x64.
// R24 taught: gemm's 13.6us (158 TF, 6% peak) is not the barrier COUNT (dbuf
// null) but work-per-barrier-segment: R18 had only 2 MFMAs between barriers.
// R25: 512 blocks (2/CU), per wave 2 col-positions -> 8 MFMAs + 12 ds_read
// per K-iter (4x amortization), staged prefetch 6 uint4 = 24 regs (no spill,
// plain bounds — R17/R18 lesson). Same GSTR=136 stride (proven). Per-element
// accumulation order identical (ascending k-slices, even->acc0 odd->acc1)
// -> bitwise identical. branch reverted to byte-identical R18 (setprio null).
// prep unchanged. absmax must stay exactly 0.03125.

typedef _Float16 half8 __attribute__((ext_vector_type(8)));
typedef float floatx4 __attribute__((ext_vector_type(4)));
typedef float floatx2 __attribute__((ext_vector_type(2)));

union U4H8 { uint4 u; half8 h; };
union PKH8 { uint4 u; _Float16 h[8]; };
union PKH4 { uint2 u; _Float16 h[4]; };

// ---------------------------------------------------------------- prep
// blocks 0..2047: hlhr (fp16): seg0 HL_chg(+b0c), seg1 HR_chg,
//                 seg2 HL_dg(+b0d), seg3 HR_dg; each [1024][128]
// blocks 2048..2111: w1frag[br][f=mt*4+ks][lane][j] =
//                 f16( W1[ks*32+(lane>>4)*8+j][mt*16+(lane&15)] )  (A-layout of W1^T)
__global__ __launch_bounds__(256) void prep(
    const float* __restrict__ Xch, const float* __restrict__ Xg,
    const float* __restrict__ Xd,
    const float* __restrict__ Wc0, const float* __restrict__ bc0,
    const float* __restrict__ Wd0, const float* __restrict__ bd0,
    const float* __restrict__ W1c, const float* __restrict__ W1d,
    _Float16* __restrict__ hlhr, _Float16* __restrict__ w1frag)
{
    int bid = blockIdx.x;
    if (bid < 2048) {
        int t = bid * 256 + threadIdx.x;   // 524288 threads
        int seg = t >> 17;
        int i = (t >> 7) & 1023;
        int k = t & 127;
        const float* X;
        const float* W;
        float s = 0.f;
        int wo = 0;
        if (seg == 0)      { X = Xch; W = Wc0; s = bc0[k]; }
        else if (seg == 1) { X = Xg;  W = Wc0; wo = 5; }
        else if (seg == 2) { X = Xg;  W = Wd0; s = bd0[k]; }
        else               { X = Xd;  W = Wd0; wo = 5; }
#pragma unroll
        for (int j = 0; j < 5; ++j)
            s += X[i * 5 + j] * W[(wo + j) * 128 + k];
        hlhr[t] = (_Float16)s;   // fp32 dot, one RNE round to fp16
    } else {
        int t = (bid - 2048) * 256 + threadIdx.x;   // 16384 threads
        int br   = t >> 13;
        int f    = (t >> 9) & 15;
        int lane = (t >> 3) & 63;
        int j    = t & 7;
        int mt = f >> 2, ks = f & 3;
        int row = ks * 32 + (lane >> 4) * 8 + j;    // k of W1
        int col = mt * 16 + (lane & 15);            // n of W1
        const float* W = br ? W1d : W1c;
        w1frag[t] = (_Float16)W[row * 64 + col];
    }
}

// ---------------------------------------------------------------- branch
#define LC 16          // l-values per block
#define PSTRIDE 69     // part[] pair stride in floats: 4 quads * 17 + 1

__global__ __launch_bounds__(256, 2) void branch_kernel(
    const _Float16* __restrict__ hlhr,
    const float* __restrict__ b1_chg, const float* __restrict__ wr_chg, const float* __restrict__ br_chg,
    const float* __restrict__ b1_dg,  const float* __restrict__ wr_dg,  const float* __restrict__ br_dg,
    const _Float16* __restrict__ w1frag,
    float* __restrict__ d_out,
    _Float16* __restrict__ wsh)   // [0:1M) Achg f16 [ch][g], [1M:2M) AgdT f16 [d][g]
{
    __shared__ _Float16 hl_tile[LC * 128];        // 4 KB
    __shared__ float part[64 * PSTRIDE];          // per-quad y partials [p][q*17+li] (17.7 KB)

    const int bz = blockIdx.z;
    const _Float16* HL = hlhr + (bz ? 262144 : 0);
    const _Float16* HR = hlhr + (bz ? 393216 : 131072);
    const float* b1 = bz ? b1_dg : b1_chg;
    const float* wr = bz ? wr_dg : wr_chg;
    const float brv = bz ? br_dg[0] : br_chg[0];
    float* outA = d_out + (bz ? 2097152 : 1048576);
    _Float16* outB = wsh + (bz ? 1048576 : 0);

    const int tid = threadIdx.x;
    const int lane = tid & 63, wave = tid >> 6;
    const int m = lane & 15, quad = lane >> 4;
    const int lbase = blockIdx.y * LC;
    const int rbase = blockIdx.x * 64;
    const int rm = rbase + wave * 16 + m;   // this lane's pair (column)
    const int p = wave * 16 + m;            // pair index within block

    {   // stage hl tile (fp16): LC*128 halves = 256 uint4
        const uint4* src = (const uint4*)(HL + lbase * 128);
        uint4* dst = (uint4*)hl_tile;
        dst[tid] = src[tid];
    }

    // hr in B-frag k-order (fp16): k = ks*32 + quad*8 + j
    half8 hr16[4];
#pragma unroll
    for (int ks = 0; ks < 4; ++ks)
        hr16[ks] = *(const half8*)(HR + rm * 128 + ks * 32 + quad * 8);

    // W1^T A-fragments (constant across the loop)
    half8 w1f[4][4];   // [mt][ks]
    {
        const uint4* wf = (const uint4*)(w1frag + bz * 8192);
#pragma unroll
        for (int f = 0; f < 16; ++f) {
            U4H8 t; t.u = wf[f * 64 + lane];
            w1f[f >> 2][f & 3] = t.h;
        }
    }

    // per-lane n-slice constants: n = mt*16 + quad*4 + r
    floatx4 b1q[4], wr4[4];
#pragma unroll
    for (int mt = 0; mt < 4; ++mt) {
        b1q[mt] = *(const floatx4*)(b1 + mt * 16 + quad * 4);
        wr4[mt] = *(const floatx4*)(wr + mt * 16 + quad * 4);
    }

    const floatx4 z4 = (floatx4){0.f, 0.f, 0.f, 0.f};
    half8 hz;
#pragma unroll
    for (int j = 0; j < 8; ++j) hz[j] = (_Float16)0.f;

    __syncthreads();

#pragma unroll 2
    for (int li = 0; li < LC; ++li) {
        const _Float16* hlp = hl_tile + li * 128;

        // h = relu(hl16 + hr16) in packed fp16 -> B-fragments
        half8 bfr[4];
#pragma unroll
        for (int ks = 0; ks < 4; ++ks) {
            half8 hl8 = *(const half8*)(hlp + ks * 32 + quad * 8);
            bfr[ks] = __builtin_elementwise_max(hl8 + hr16[ks], hz);
        }

        // b1 folded into the FIRST MFMA's C operand (no acc-init copies;
        // same per-element accumulation order as acc=b1q + ks=0..3 chain).
        floatx4 acc[4];
#pragma unroll
        for (int mt = 0; mt < 4; ++mt)
            acc[mt] = __builtin_amdgcn_mfma_f32_16x16x32_f16(w1f[mt][0], bfr[0], b1q[mt], 0, 0, 0);
#pragma unroll
        for (int ks = 1; ks < 4; ++ks)
#pragma unroll
            for (int mt = 0; mt < 4; ++mt)
                acc[mt] = __builtin_amdgcn_mfma_f32_16x16x32_f16(w1f[mt][ks], bfr[ks], acc[mt], 0, 0, 0);

        // acc[mt][r] = h1[pair rm][n = mt*16+quad*4+r] + b1;  dot with Wr.
        floatx4 y4 = z4;
#pragma unroll
        for (int mt = 0; mt < 4; ++mt)
            y4 += __builtin_elementwise_max(acc[mt], z4) * wr4[mt];
        float y = (y4[0] + y4[1]) + (y4[2] + y4[3]);

        // quad partial; cross-quad reduction deferred to epilogue.
        part[p * PSTRIDE + quad * 17 + li] = y;
    }

    __syncthreads();

    // ---- epilogue pass 1: [li][pp] order -> outA (both) + outB (bz==0)
    {
        int li = tid >> 4;            // 0..15
        int p0 = (tid & 15) * 4;      // 0,4,..,60
        float v[4];
#pragma unroll
        for (int j = 0; j < 4; ++j) {
            const float* q = part + (p0 + j) * PSTRIDE + li;
            float yv = ((q[0] + q[17]) + (q[34] + q[51])) + brv;
            v[j] = yv > 0.f ? yv : (__expf(yv) - 1.f);   // elu
        }
        *(float4*)(outA + (lbase + li) * 1024 + rbase + p0) =
            make_float4(v[0], v[1], v[2], v[3]);
        if (bz == 0) {
            PKH4 pk;
#pragma unroll
            for (int j = 0; j < 4; ++j) pk.h[j] = (_Float16)v[j];
            *(uint2*)(outB + (lbase + li) * 1024 + rbase + p0) = pk.u;
        }
    }
    // ---- epilogue pass 2 (bz==1): [pp][li] order -> AgdT transposed
    if (bz == 1) {
        int pp = tid >> 2;            // 0..63
        int li0 = (tid & 3) * 4;      // 0,4,8,12
        PKH4 pk;
#pragma unroll
        for (int j = 0; j < 4; ++j) {
            const float* q = part + pp * PSTRIDE + li0 + j;
            float yv = ((q[0] + q[17]) + (q[34] + q[51])) + brv;
            float v = yv > 0.f ? yv : (__expf(yv) - 1.f);
            pk.h[j] = (_Float16)v;
        }
        *(uint2*)(outB + (rbase + pp) * 1024 + lbase + li0) = pk.u;
    }
}

// ---------------------------------------------------------------- final GEMM + sigmoid
// C[ch][d] = sum_g Achg[ch][g]*Agd[g][d]; fp16 MFMA, fp32 accum.
// R25: 32x64 tiles, 512 blocks (2/CU), BK=128. Per wave: rows wrow..wrow+16,
// cols wcol..wcol+32 (2 positions) -> 8 MFMAs + 12 ds_read_b128 per K-iter
// (4x R18's work per barrier segment). Staged prefetch 6 uint4 = 24 regs
// (plain bounds, no spill). Per output element the k-slices accumulate
// ascending with even->acc0 / odd->acc1 -> bitwise identical to R18/R9.
#define GSTR 136   // LDS row stride in halves (128 + 8 pad)

__global__ __launch_bounds__(256) void gemm_sig(
    const _Float16* __restrict__ Ahf,   // [1024][1024] ch x g
    const _Float16* __restrict__ BThf,  // [1024][1024] d x g
    float* __restrict__ out0)
{
    __shared__ _Float16 At[32 * GSTR];   // 8.7 KB
    __shared__ _Float16 Bt[64 * GSTR];   // 17.4 KB

    const int tid = threadIdx.x, lane = tid & 63, wave = tid >> 6;
    const int m = lane & 15, quad = lane >> 4;
    const int chbase = blockIdx.y * 32, dbase = blockIdx.x * 64;
    const int wrow = (wave >> 1) * 16;        // 0 or 16
    const int wcol = (wave & 1) * 32;         // 0 or 32; 2 col-positions of 16

    floatx4 acc[2][2];                        // [position][parity]
#pragma unroll
    for (int pp = 0; pp < 2; ++pp) {
        acc[pp][0] = (floatx4){0.f, 0.f, 0.f, 0.f};
        acc[pp][1] = (floatx4){0.f, 0.f, 0.f, 0.f};
    }

    // staging maps (BK=128 halves = 16 uint4 per row):
    //  A: 32 rows, row=tid>>3, c8=tid&7 covers uint4 cols {c8, c8+8}
    //  B: 64 rows, rowb=tid>>2, c4=tid&3 covers uint4 cols {c4,c4+4,c4+8,c4+12}
    const int row = tid >> 3, c8 = tid & 7;
    const int rowb = tid >> 2, c4 = tid & 3;
    const _Float16* gA = Ahf + (chbase + row) * 1024 + c8 * 8;
    const _Float16* gB = BThf + (dbase + rowb) * 1024 + c4 * 8;

    uint4 ra0 = *(const uint4*)(gA);
    uint4 ra1 = *(const uint4*)(gA + 64);
    uint4 rb0 = *(const uint4*)(gB);
    uint4 rb1 = *(const uint4*)(gB + 32);
    uint4 rb2 = *(const uint4*)(gB + 64);
    uint4 rb3 = *(const uint4*)(gB + 96);

#pragma unroll
    for (int kb = 0; kb < 8; ++kb) {
        *(uint4*)(At + row * GSTR + c8 * 8) = ra0;
        *(uint4*)(At + row * GSTR + 64 + c8 * 8) = ra1;
        *(uint4*)(Bt + rowb * GSTR + c4 * 8) = rb0;
        *(uint4*)(Bt + rowb * GSTR + 32 + c4 * 8) = rb1;
        *(uint4*)(Bt + rowb * GSTR + 64 + c4 * 8) = rb2;
        *(uint4*)(Bt + rowb * GSTR + 96 + c4 * 8) = rb3;
        __syncthreads();

        // prefetch next K-block (hides under the MFMA phase)
        if (kb < 7) {
            ra0 = *(const uint4*)(gA + (kb + 1) * 128);
            ra1 = *(const uint4*)(gA + (kb + 1) * 128 + 64);
            rb0 = *(const uint4*)(gB + (kb + 1) * 128);
            rb1 = *(const uint4*)(gB + (kb + 1) * 128 + 32);
            rb2 = *(const uint4*)(gB + (kb + 1) * 128 + 64);
            rb3 = *(const uint4*)(gB + (kb + 1) * 128 + 96);
        }

        // 4 k-slices of K=32; global slice s = kb*4+ks. Even s -> acc[][0],
        // odd s -> acc[][1], ascending -> bitwise identical accumulation.
#pragma unroll
        for (int ks = 0; ks < 4; ks += 2) {
            half8 a0 = *(const half8*)(At + (wrow + m) * GSTR + ks * 32 + quad * 8);
            half8 a1 = *(const half8*)(At + (wrow + m) * GSTR + (ks + 1) * 32 + quad * 8);
#pragma unroll
            for (int pp = 0; pp < 2; ++pp) {
                half8 b0 = *(const half8*)(Bt + (wcol + pp * 16 + m) * GSTR + ks * 32 + quad * 8);
                half8 b1 = *(const half8*)(Bt + (wcol + pp * 16 + m) * GSTR + (ks + 1) * 32 + quad * 8);
                acc[pp][0] = __builtin_amdgcn_mfma_f32_16x16x32_f16(a0, b0, acc[pp][0], 0, 0, 0);
                acc[pp][1] = __builtin_amdgcn_mfma_f32_16x16x32_f16(a1, b1, acc[pp][1], 0, 0, 0);
            }
        }
        __syncthreads();
    }

#pragma unroll
    for (int pp = 0; pp < 2; ++pp) {
        floatx4 a = acc[pp][0] + acc[pp][1];
#pragma unroll
        for (int r = 0; r < 4; ++r) {
            int row_o = chbase + wrow + quad * 4 + r;
            int col_o = dbase + wcol + pp * 16 + m;
            // sigmoid via fast exp + hw rcp (~1e-7 drift, well under tolerance)
            float e = __expf(-a[r]);
            out0[row_o * 1024 + col_o] = __builtin_amdgcn_rcpf(1.f + e);
        }
    }
}

// ---------------------------------------------------------------- launch
extern "C" void kernel_launch(void* const* d_in, const int* in_sizes, int n_in,
                              void* d_out, int out_size, void* d_ws, size_t ws_size,
                              hipStream_t stream) {
    const float* Xch = (const float*)d_in[0];
    const float* Xg  = (const float*)d_in[1];
    const float* Xd  = (const float*)d_in[2];
    const float* Wc0 = (const float*)d_in[3];
    const float* bc0 = (const float*)d_in[4];
    const float* Wc1 = (const float*)d_in[5];
    const float* bc1 = (const float*)d_in[6];
    const float* Wcr = (const float*)d_in[7];
    const float* bcr = (const float*)d_in[8];
    const float* Wd0 = (const float*)d_in[9];
    const float* bd0 = (const float*)d_in[10];
    const float* Wd1 = (const float*)d_in[11];
    const float* bd1 = (const float*)d_in[12];
    const float* Wdr = (const float*)d_in[13];
    const float* bdr = (const float*)d_in[14];

    float* out = (float*)d_out;
    _Float16* hlhr = (_Float16*)d_ws;            // 4x1024x128 fp16 = 1 MB
    _Float16* wsh = hlhr + 524288;               // Achg f16 1M + AgdT f16 1M
    _Float16* w1frag = wsh + 2097152;            // 16384 f16

    prep<<<2112, 256, 0, stream>>>(Xch, Xg, Xd, Wc0, bc0, Wd0, bd0, Wc1, Wd1,
                                   hlhr, w1frag);

    dim3 gb(16, 64, 2);   // (r-chunks of 64, l-chunks of 16, branch)
    branch_kernel<<<gb, 256, 0, stream>>>(hlhr, bc1, Wcr, bcr, bd1, Wdr, bdr,
                                          w1frag, out, wsh);

    dim3 gg(16, 32);      // (d-chunks of 64, ch-chunks of 32)
    gemm_sig<<<gg, 256, 0, stream>>>(wsh, wsh + 1048576, out);
}